// Round 7
// baseline (395.370 us; speedup 1.0000x reference)
//
#include <hip/hip_runtime.h>
#include <hip/hip_fp16.h>

#define B_ 16384
#define T_ 128
#define E_ 32
#define H_ 128
#define G3_ 384
#define V_ 30001
#define D_ 128
#define C_ 3

#define LOG2E 1.44269504088896340736f

typedef _Float16 f16;
typedef f16 f16x4 __attribute__((ext_vector_type(4)));
typedef f16 f16x8 __attribute__((ext_vector_type(8)));
typedef float f32x4 __attribute__((ext_vector_type(4)));
typedef unsigned int u32;

// ---- LDS layout (bytes), 512-thread block, 16 batch rows ----
#define HPITCH   272                 // h row pitch: 128 f16 + pad (16B aligned)
#define H0_OFF   0                   // 16*272 = 4352
#define H1_OFF   4352
#define TOK_OFF  8704                // u32 byte-offsets, [t=128][r=16] = 8192
#define DBUF_OFF 16896               // head dbuf f32 [16][132] = 8448
#define LDS_TOTAL 25344

__device__ __forceinline__ float frcp_(float x)  { return __builtin_amdgcn_rcpf(x); }
__device__ __forceinline__ float fexp2_(float x) { return __builtin_amdgcn_exp2f(x); }

// ---------------- Kernel 1: pre-scaled table, [v][slot][c] = original g-order ----------------
// embW[v*384 + g], g = slot*128 + c; slot 0=z,1=r (x -log2e), 2=h (x +2log2e)
#define K1_ROWS 8
__global__ __launch_bounds__(384) void embw_kernel(
    const float* __restrict__ emb,   // [V][32]
    const float* __restrict__ W,     // [32][384]
    const float* __restrict__ b_in,  // [384] (= b row 0)
    f16* __restrict__ embW)          // [V][384] f16 pre-scaled
{
    __shared__ float sW[E_][G3_];
    __shared__ float sE[K1_ROWS][E_];
    const int g = threadIdx.x;           // 0..383
    #pragma unroll
    for (int e = 0; e < E_; ++e) sW[e][g] = W[e * G3_ + g];
    const int v0 = blockIdx.x * K1_ROWS;
    for (int idx = g; idx < K1_ROWS * E_; idx += 384) {
        int rr = idx >> 5, ee = idx & 31;
        int v = v0 + rr;
        sE[rr][ee] = (v < V_) ? emb[v * E_ + ee] : 0.f;
    }
    __syncthreads();
    const float bg = b_in[g];
    const float sc = (g >= 256) ? (2.f * LOG2E) : (-LOG2E);
    #pragma unroll
    for (int rr = 0; rr < K1_ROWS; ++rr) {
        int v = v0 + rr;
        if (v >= V_) break;
        float acc = bg;
        #pragma unroll
        for (int e = 0; e < E_; ++e) acc = fmaf(sE[rr][e], sW[e][g], acc);
        embW[(size_t)v * G3_ + g] = (f16)(acc * sc);
    }
}

// ---------------- Kernel 2: transposed-output MFMA GRU ----------------
// 1024 blocks x 512 threads (8 waves). Block owns 16 batch rows; wave w owns
// gate-cols [16w,16w+16) of each 128-col gate block. Computes rec^T = U^T @ h^T:
//   A (persistent, 48 VGPR): lane l holds U[kt*32+q*8+j][gt*128 + w*16 + cl]
//   B (LDS): lane l holds h[batch=cl][kt*32+q*8+j]  (b128 read, pitch 272)
//   D: lane l reg i -> (gate-col w*16+4q+i, batch cl)
// => each lane updates h[cl][w*16+4q..+3]: 1 token read, 1 mask, 1 b64 h-write.
__global__ __launch_bounds__(512, 4) void gru_mfma_kernel(
    const int*   __restrict__ tokens,  // [B][T]
    const f16*   __restrict__ embW,    // [V][384] f16 pre-scaled (includes b0)
    const float* __restrict__ U,       // [128][384]
    const float* __restrict__ b,       // [2][384]
    const float* __restrict__ W1,      // [128][128]
    const float* __restrict__ b1,      // [128]
    const float* __restrict__ Wout,    // [128][3]
    const float* __restrict__ bout,    // [3]
    float* __restrict__ out)           // [B][3]
{
    __shared__ char lds[LDS_TOTAL];
    const int tid = threadIdx.x;
    const int w   = tid >> 6;       // wave = 16-gate-col group, 0..7
    const int l   = tid & 63;
    const int cl  = l & 15;         // batch row owned by this lane
    const int q   = l >> 4;         // 0..3
    const int R0  = blockIdx.x * 16;
    const int c0  = w * 16 + 4 * q; // lane's 4 gate-cols base (within 128)

    // ---- stage token byte-offsets (tok*768 = f16 row bytes), [t][r] ----
    for (int idx = tid; idx < 16 * T_; idx += 512) {
        int r = idx >> 7, t = idx & 127;
        u32 tok = (u32)tokens[(size_t)(R0 + r) * T_ + t];
        *(u32*)(&lds[TOK_OFF + t * 64 + r * 4]) = tok * 768u;
    }
    // ---- zero h buffer 0 ----
    for (int idx = tid; idx < H1_OFF / 4; idx += 512)
        ((float*)(lds + H0_OFF))[idx] = 0.f;

    // ---- persistent U^T A-fragments, pre-scaled ----
    // Af[gt][kt]: lane holds sc(gt) * U[kt*32 + q*8 + j][gt*128 + w*16 + cl]
    f16x8 Af[3][4];
    #pragma unroll
    for (int gt = 0; gt < 3; ++gt) {
        const float sc = (gt == 2) ? (2.f * LOG2E) : (-LOG2E);
        const int n = gt * 128 + w * 16 + cl;
        #pragma unroll
        for (int kt = 0; kt < 4; ++kt) {
            const int k0 = kt * 32 + q * 8;
            f16x8 fr;
            #pragma unroll
            for (int j = 0; j < 8; ++j)
                fr[j] = (f16)(U[(size_t)(k0 + j) * G3_ + n] * sc);
            Af[gt][kt] = fr;
        }
    }

    // ---- pre-scaled recurrent biases for this lane's 4 gate-cols (C-operand init) ----
    f32x4 bz4, br4, bh4;
    #pragma unroll
    for (int i = 0; i < 4; ++i) {
        bz4[i] = -LOG2E * b[G3_ + c0 + i];
        br4[i] = -LOG2E * b[G3_ + 128 + c0 + i];
        bh4[i] = 2.f * LOG2E * b[G3_ + 256 + c0 + i];
    }

    float hreg[4];
    #pragma unroll
    for (int i = 0; i < 4; ++i) hreg[i] = 0.f;

    __syncthreads();

    const char* embWb = (const char*)embW;
    const int colb = c0 * 2;            // byte offset of slot-slice within a slot block

    // prefetch t=0: this lane's row token offset + 3 slot slices
    u32 offc = *(const u32*)(&lds[TOK_OFF + cl * 4]);
    f16x4 xzc = *(const f16x4*)(embWb + offc + colb);
    f16x4 xrc = *(const f16x4*)(embWb + offc + colb + 256);
    f16x4 xhc = *(const f16x4*)(embWb + offc + colb + 512);

    int cur = 0;
    for (int t = 0; t < T_; ++t) {
        const char* hb = lds + (cur ? H1_OFF : H0_OFF);
        char*       hn = lds + (cur ? H0_OFF : H1_OFF);

        // ---- prefetch t+1 (h-independent; lands under MFMAs) ----
        u32 offn = offc;
        f16x4 xzn = xzc, xrn = xrc, xhn = xhc;
        if (t + 1 < T_) {
            offn = *(const u32*)(&lds[TOK_OFF + (t + 1) * 64 + cl * 4]);
            xzn = *(const f16x4*)(embWb + offn + colb);
            xrn = *(const f16x4*)(embWb + offn + colb + 256);
            xhn = *(const f16x4*)(embWb + offn + colb + 512);
        }

        // ---- rec^T = U^T @ h^T, bias via C-operand ----
        const f16x8 bf0 = *(const f16x8*)(hb + cl * HPITCH + q * 16);
        const f16x8 bf1 = *(const f16x8*)(hb + cl * HPITCH + q * 16 + 64);
        const f16x8 bf2 = *(const f16x8*)(hb + cl * HPITCH + q * 16 + 128);
        const f16x8 bf3 = *(const f16x8*)(hb + cl * HPITCH + q * 16 + 192);
        f32x4 accz = __builtin_amdgcn_mfma_f32_16x16x32_f16(Af[0][0], bf0, bz4, 0, 0, 0);
        f32x4 accr = __builtin_amdgcn_mfma_f32_16x16x32_f16(Af[1][0], bf0, br4, 0, 0, 0);
        f32x4 acch = __builtin_amdgcn_mfma_f32_16x16x32_f16(Af[2][0], bf0, bh4, 0, 0, 0);
        accz = __builtin_amdgcn_mfma_f32_16x16x32_f16(Af[0][1], bf1, accz, 0, 0, 0);
        accr = __builtin_amdgcn_mfma_f32_16x16x32_f16(Af[1][1], bf1, accr, 0, 0, 0);
        acch = __builtin_amdgcn_mfma_f32_16x16x32_f16(Af[2][1], bf1, acch, 0, 0, 0);
        accz = __builtin_amdgcn_mfma_f32_16x16x32_f16(Af[0][2], bf2, accz, 0, 0, 0);
        accr = __builtin_amdgcn_mfma_f32_16x16x32_f16(Af[1][2], bf2, accr, 0, 0, 0);
        acch = __builtin_amdgcn_mfma_f32_16x16x32_f16(Af[2][2], bf2, acch, 0, 0, 0);
        accz = __builtin_amdgcn_mfma_f32_16x16x32_f16(Af[0][3], bf3, accz, 0, 0, 0);
        accr = __builtin_amdgcn_mfma_f32_16x16x32_f16(Af[1][3], bf3, accr, 0, 0, 0);
        acch = __builtin_amdgcn_mfma_f32_16x16x32_f16(Af[2][3], bf3, acch, 0, 0, 0);

        // ---- gates (exp2-direct), one mask for all 4 elements ----
        f16x4 hv4;
        #pragma unroll
        for (int i = 0; i < 4; ++i) {
            const float z  = frcp_(1.f + fexp2_((float)xzc[i] + accz[i]));
            const float r  = frcp_(1.f + fexp2_((float)xrc[i] + accr[i]));
            const float hh = fmaf(-2.f, frcp_(1.f + fexp2_(fmaf(r, acch[i], (float)xhc[i]))), 1.f);
            const float hv = hreg[i];
            float nv = fmaf(z, hv - hh, hh);
            nv = (offc != 0u) ? nv : hv;
            hreg[i] = nv;
            hv4[i] = (f16)nv;
        }
        // one contiguous 8B write: h[cl][c0..c0+3]
        *(f16x4*)(hn + cl * HPITCH + colb) = hv4;

        __syncthreads();
        cur ^= 1;
        offc = offn; xzc = xzn; xrc = xrn; xhc = xhn;
    }
    // T_=128 even -> final h is in buffer 0

    // ---- head: d^T = W1^T @ h^T (swish), wave w owns d-cols [16w,16w+16) ----
    {
        f16x8 Wf[4];
        #pragma unroll
        for (int kt = 0; kt < 4; ++kt) {
            const int k0 = kt * 32 + q * 8;
            f16x8 fr;
            #pragma unroll
            for (int j = 0; j < 8; ++j)
                fr[j] = (f16)W1[(size_t)(k0 + j) * D_ + w * 16 + cl];
            Wf[kt] = fr;
        }
        const char* hb = lds + H0_OFF;
        f32x4 bd4;
        #pragma unroll
        for (int i = 0; i < 4; ++i) bd4[i] = b1[c0 + i];
        const f16x8 bf0 = *(const f16x8*)(hb + cl * HPITCH + q * 16);
        const f16x8 bf1 = *(const f16x8*)(hb + cl * HPITCH + q * 16 + 64);
        const f16x8 bf2 = *(const f16x8*)(hb + cl * HPITCH + q * 16 + 128);
        const f16x8 bf3 = *(const f16x8*)(hb + cl * HPITCH + q * 16 + 192);
        f32x4 dacc = __builtin_amdgcn_mfma_f32_16x16x32_f16(Wf[0], bf0, bd4, 0, 0, 0);
        dacc = __builtin_amdgcn_mfma_f32_16x16x32_f16(Wf[1], bf1, dacc, 0, 0, 0);
        dacc = __builtin_amdgcn_mfma_f32_16x16x32_f16(Wf[2], bf2, dacc, 0, 0, 0);
        dacc = __builtin_amdgcn_mfma_f32_16x16x32_f16(Wf[3], bf3, dacc, 0, 0, 0);
        // d[batch=cl][dcol c0+i], swish, one 16B store
        f32x4 sw4;
        #pragma unroll
        for (int i = 0; i < 4; ++i) {
            const float v = dacc[i];
            sw4[i] = v * frcp_(1.f + fexp2_(-LOG2E * v));
        }
        *(f32x4*)(&lds[DBUF_OFF + cl * 528 + c0 * 4]) = sw4;
    }
    __syncthreads();

    // ---- logits + softmax: wave 0, 48 lanes = 16 rows x 3 classes ----
    if (w == 0 && l < 48) {
        const int row = l & 15, ci = l >> 4;
        float acc = bout[ci];
        #pragma unroll 4
        for (int k = 0; k < D_; ++k)
            acc = fmaf(*(const float*)(&lds[DBUF_OFF + row * 528 + k * 4]),
                       Wout[k * 3 + ci], acc);
        const float v0 = __shfl(acc, row);
        const float v1 = __shfl(acc, row + 16);
        const float v2 = __shfl(acc, row + 32);
        const float mx = fmaxf(v0, fmaxf(v1, v2));
        const float e0 = fexp2_(LOG2E * (v0 - mx));
        const float e1 = fexp2_(LOG2E * (v1 - mx));
        const float e2 = fexp2_(LOG2E * (v2 - mx));
        const float inv = frcp_(e0 + e1 + e2);
        const float mine = (ci == 0) ? e0 : (ci == 1) ? e1 : e2;
        out[(size_t)(R0 + row) * 3 + ci] = mine * inv;
    }
}

extern "C" void kernel_launch(void* const* d_in, const int* in_sizes, int n_in,
                              void* d_out, int out_size, void* d_ws, size_t ws_size,
                              hipStream_t stream) {
    (void)in_sizes; (void)n_in; (void)out_size; (void)ws_size;
    const int*   tokens = (const int*)d_in[0];
    const float* emb    = (const float*)d_in[1];
    const float* W      = (const float*)d_in[2];
    const float* U      = (const float*)d_in[3];
    const float* b      = (const float*)d_in[4];
    const float* W1     = (const float*)d_in[5];
    const float* b1     = (const float*)d_in[6];
    const float* Wout   = (const float*)d_in[7];
    const float* bout   = (const float*)d_in[8];
    float* out  = (float*)d_out;
    f16*   embW = (f16*)d_ws;   // [V][384] f16 = 23 MB scratch

    hipLaunchKernelGGL(embw_kernel, dim3((V_ + K1_ROWS - 1) / K1_ROWS), dim3(384), 0, stream,
                       emb, W, b, embW);
    hipLaunchKernelGGL(gru_mfma_kernel, dim3(B_ / 16), dim3(512), 0, stream,
                       tokens, embW, U, b, W1, b1, Wout, bout, out);
}